// Round 8
// baseline (439.354 us; speedup 1.0000x reference)
//
#include <hip/hip_runtime.h>
#include <math.h>

#define N_NODES 100000
#define N_EDGES 3200000
#define IN_F 256
#define OUT_F 64
#define LRELU_ALPHA 0.2f
#define NBKT 782   // ceil(100000/128) coarse buckets of 128 nodes
#define CAP 4480   // bucket capacity: mean 4096 + 6 sigma (sigma=64)

typedef unsigned short u16;
typedef __attribute__((ext_vector_type(8))) short short8;
typedef __attribute__((ext_vector_type(4))) float floatx4;

__device__ inline u16 f2bf(float f) {  // RNE fp32 -> bf16
  unsigned u = __float_as_uint(f);
  u += 0x7FFFu + ((u >> 16) & 1u);
  return (u16)(u >> 16);
}
__device__ inline float bf2f(u16 h) {
  return __uint_as_float(((unsigned)h) << 16);
}

// ---------------------------------------------------------------------------
// prep: blocks 0..63 convert W to bf16; block 64 zeros the bucket fill ctrs
// ---------------------------------------------------------------------------
__global__ __launch_bounds__(256) void k_prep(const float* __restrict__ W,
                                              u16* __restrict__ Wbf,
                                              int* __restrict__ sfill,
                                              int* __restrict__ dfill) {
  if (blockIdx.x < 64) {
    int i = blockIdx.x * 256 + threadIdx.x;
    Wbf[i] = f2bf(W[i]);
  } else {
    for (int i = threadIdx.x; i < NBKT; i += 256) {
      sfill[i] = 0;
      dfill[i] = 0;
    }
  }
}

// ---------------------------------------------------------------------------
// place: pure index bucketing (no ex — recomputed downstream, so this kernel
// is independent of k_linear). Writes 4 B packed entries into padded buckets.
// packS = d | (s&127)<<17   src-bucketed
// packD = s | (d&127)<<17   dst-bucketed
// ---------------------------------------------------------------------------
#define EPT_P 32
__global__ __launch_bounds__(1024) void k_place(
    const int* __restrict__ src, const int* __restrict__ dst,
    int* __restrict__ sfill, int* __restrict__ dfill,
    int* __restrict__ packS, int* __restrict__ packD) {
  __shared__ int lcS[NBKT];
  __shared__ int lcD[NBKT];
  __shared__ int lbS[NBKT];
  __shared__ int lbD[NBKT];
  const int t = threadIdx.x;
  for (int i = t; i < NBKT; i += 1024) {
    lcS[i] = 0;
    lcD[i] = 0;
  }
  __syncthreads();

  const int base = blockIdx.x * (1024 * EPT_P);
  // phase 1: count per-bucket
#pragma unroll 4
  for (int j = 0; j < EPT_P; j++) {
    int e = base + j * 1024 + t;
    if (e < N_EDGES) {
      atomicAdd(&lcS[src[e] >> 7], 1);
      atomicAdd(&lcD[dst[e] >> 7], 1);
    }
  }
  __syncthreads();
  // phase 2: reserve contiguous chunks (one global atomic per block-bucket)
  for (int i = t; i < NBKT; i += 1024) {
    int c = lcS[i];
    if (c) lbS[i] = atomicAdd(&sfill[i], c);
    int c2 = lcD[i];
    if (c2) lbD[i] = atomicAdd(&dfill[i], c2);
  }
  __syncthreads();
  for (int i = t; i < NBKT; i += 1024) {
    lcS[i] = 0;
    lcD[i] = 0;
  }
  __syncthreads();
  // phase 3: re-read (L2-hot) and scatter packed indices
#pragma unroll 4
  for (int j = 0; j < EPT_P; j++) {
    int e = base + j * 1024 + t;
    if (e < N_EDGES) {
      int s = src[e];
      int d = dst[e];
      int bs = s >> 7;
      int bd = d >> 7;
      int r = atomicAdd(&lcS[bs], 1);
      packS[(size_t)bs * CAP + lbS[bs] + r] = d | ((s & 127) << 17);
      int r2 = atomicAdd(&lcD[bd], 1);
      packD[(size_t)bd * CAP + lbD[bd] + r2] = s | ((d & 127) << 17);
    }
  }
}

// ---------------------------------------------------------------------------
// linear via bf16 MFMA: h = x@W^T + b (stored bf16); s1 = h.a1; s2 = h.a2
// ---------------------------------------------------------------------------
__global__ __launch_bounds__(256) void k_linear(
    const float* __restrict__ x, const u16* __restrict__ Wbf,
    const float* __restrict__ b, const float* __restrict__ a,
    u16* __restrict__ hbf, float* __restrict__ s1, float* __restrict__ s2) {
  __shared__ u16 Wlds[64 * 264];

  const int t = threadIdx.x;
#pragma unroll
  for (int p = 0; p < 8; p++) {
    int c = p * 256 + t;
    int row = c >> 5;
    int kc = (c & 31) * 8;
    *(short8*)&Wlds[row * 264 + kc] = *(const short8*)&Wbf[row * 256 + kc];
  }
  __syncthreads();

  const int w = t >> 6;
  const int lane = t & 63;
  const int col = lane & 15;
  const int q = lane >> 4;
  const int m0 = blockIdx.x * 64 + w * 16;

  floatx4 acc[4];
#pragma unroll
  for (int nt = 0; nt < 4; nt++) acc[nt] = (floatx4){0.f, 0.f, 0.f, 0.f};

  int mrow = m0 + col;
  if (mrow > N_NODES - 1) mrow = N_NODES - 1;
  const float* xrow = x + (size_t)mrow * IN_F + q * 8;

#pragma unroll
  for (int kk = 0; kk < 8; kk++) {
    float4 f0 = *(const float4*)(xrow + kk * 32);
    float4 f1 = *(const float4*)(xrow + kk * 32 + 4);
    short8 af;
    af[0] = (short)f2bf(f0.x);
    af[1] = (short)f2bf(f0.y);
    af[2] = (short)f2bf(f0.z);
    af[3] = (short)f2bf(f0.w);
    af[4] = (short)f2bf(f1.x);
    af[5] = (short)f2bf(f1.y);
    af[6] = (short)f2bf(f1.z);
    af[7] = (short)f2bf(f1.w);
#pragma unroll
    for (int nt = 0; nt < 4; nt++) {
      short8 bfr = *(const short8*)&Wlds[(nt * 16 + col) * 264 + kk * 32 + q * 8];
      acc[nt] = __builtin_amdgcn_mfma_f32_16x16x32_bf16(af, bfr, acc[nt], 0, 0, 0);
    }
  }

  float bv[4], a1v[4], a2v[4];
#pragma unroll
  for (int nt = 0; nt < 4; nt++) {
    bv[nt] = b[nt * 16 + col];
    a1v[nt] = a[nt * 16 + col];
    a2v[nt] = a[OUT_F + nt * 16 + col];
  }
#pragma unroll
  for (int r = 0; r < 4; r++) {
    int node = m0 + q * 4 + r;
    float p1 = 0.f, p2 = 0.f;
#pragma unroll
    for (int nt = 0; nt < 4; nt++) {
      float hv = acc[nt][r] + bv[nt];
      if (node < N_NODES) hbf[(size_t)node * OUT_F + nt * 16 + col] = f2bf(hv);
      p1 = fmaf(hv, a1v[nt], p1);
      p2 = fmaf(hv, a2v[nt], p2);
    }
#pragma unroll
    for (int s = 1; s < 16; s <<= 1) {
      p1 += __shfl_xor(p1, s, 16);
      p2 += __shfl_xor(p2, s, 16);
    }
    if (col == 0 && node < N_NODES) {
      s1[node] = p1;
      s2[node] = p2;
    }
  }
}

// ---------------------------------------------------------------------------
// denom: block per dst-bucket; recompute ex from s1 gather + LDS s2; write
// RECIPROCAL denom. No global atomics.
// ---------------------------------------------------------------------------
__global__ __launch_bounds__(256) void k_denom(const int* __restrict__ dfill,
                                               const int* __restrict__ packD,
                                               const float* __restrict__ s1,
                                               const float* __restrict__ s2,
                                               float* __restrict__ denom_r) {
  __shared__ float lacc[128];
  __shared__ float s2l[128];
  const int t = threadIdx.x;
  const int bkt = blockIdx.x;
  if (t < 128) {
    lacc[t] = 0.f;
    int node = bkt * 128 + t;
    s2l[t] = (node < N_NODES) ? s2[node] : 0.f;
  }
  __syncthreads();
  int beg = bkt * CAP;
  int end = beg + dfill[bkt];
  for (int i = beg + t; i < end; i += 256) {
    int pk = packD[i];
    int s = pk & 0x1FFFF;
    int dl = pk >> 17;  // 24-bit value, shift is fine
    float v = s1[s] + s2l[dl];
    v = v > 0.f ? v : LRELU_ALPHA * v;
    atomicAdd(&lacc[dl], __expf(v));
  }
  __syncthreads();
  if (t < 128) {
    int node = bkt * 128 + t;
    if (node < N_NODES) denom_r[node] = 1.0f / lacc[t];
  }
}

// ---------------------------------------------------------------------------
// sort2: block per src-bucket. Node-exact sort via LDS histogram + scan +
// LDS-atomic rank. Recomputes ex (LDS s1, gathered s2), folds 1/denom.
// Emits rowbe[node] = (beg,end) and pairA = (att, d).
// ---------------------------------------------------------------------------
__global__ __launch_bounds__(256) void k_sort2(
    const int* __restrict__ sfill, const int* __restrict__ packS,
    const float* __restrict__ s1, const float* __restrict__ s2,
    const float* __restrict__ denom_r, float2* __restrict__ pairA,
    int2* __restrict__ rowbe) {
  __shared__ int lcnt[128];
  __shared__ int cursor[128];
  __shared__ float s1l[128];
  __shared__ int w0tot;
  const int t = threadIdx.x;
  const int bkt = blockIdx.x;
  if (t < 128) {
    lcnt[t] = 0;
    int node = bkt * 128 + t;
    s1l[t] = (node < N_NODES) ? s1[node] : 0.f;
  }
  __syncthreads();

  const int beg = bkt * CAP;
  const int end = beg + sfill[bkt];

  for (int i = beg + t; i < end; i += 256) {
    atomicAdd(&lcnt[packS[i] >> 17], 1);
  }
  __syncthreads();

  const int lane = t & 63;
  int v = (t < 128) ? lcnt[t] : 0;
  int val = v;
#pragma unroll
  for (int ofs = 1; ofs < 64; ofs <<= 1) {
    int u = __shfl_up(val, ofs, 64);
    if (lane >= ofs) val += u;
  }
  if (t == 63) w0tot = val;
  __syncthreads();
  int excl = val - v + ((t >= 64 && t < 128) ? w0tot : 0);
  if (t < 128) {
    cursor[t] = beg + excl;
    int node = bkt * 128 + t;
    if (node < N_NODES) rowbe[node] = make_int2(beg + excl, beg + excl + v);
  }
  __syncthreads();

  for (int i = beg + t; i < end; i += 256) {
    int pk = packS[i];
    int sl = pk >> 17;
    int d = pk & 0x1FFFF;
    float ev = s1l[sl] + s2[d];
    ev = ev > 0.f ? ev : LRELU_ALPHA * ev;
    float att = __expf(ev) * denom_r[d];
    int pos = atomicAdd(&cursor[sl], 1);
    pairA[pos] = make_float2(att, __int_as_float(d));
  }
}

// ---------------------------------------------------------------------------
// aggregate: 4 nodes per wave (16 lanes/node, ushort4 = 4 features/lane).
// ---------------------------------------------------------------------------
__global__ __launch_bounds__(256) void k_aggregate(
    const int2* __restrict__ rowbe, const float2* __restrict__ pairA,
    const u16* __restrict__ hbf, float* __restrict__ out) {
  int wid = (blockIdx.x * 256 + threadIdx.x) >> 6;
  int lane = threadIdx.x & 63;
  int g = lane >> 4;
  int sl = lane & 15;
  int node = wid * 4 + g;
  int2 be = (node < N_NODES) ? rowbe[node] : make_int2(0, 0);
  float4 acc = make_float4(0.f, 0.f, 0.f, 0.f);
  int i = be.x;
  const int end = be.y;
  for (; i + 1 < end; i += 2) {
    float2 p0 = pairA[i];
    float2 p1 = pairA[i + 1];
    int d0 = __float_as_int(p0.y);
    int d1 = __float_as_int(p1.y);
    ushort4 q0 = *(const ushort4*)&hbf[(size_t)d0 * OUT_F + sl * 4];
    ushort4 q1 = *(const ushort4*)&hbf[(size_t)d1 * OUT_F + sl * 4];
    acc.x = fmaf(p0.x, bf2f(q0.x), acc.x);
    acc.y = fmaf(p0.x, bf2f(q0.y), acc.y);
    acc.z = fmaf(p0.x, bf2f(q0.z), acc.z);
    acc.w = fmaf(p0.x, bf2f(q0.w), acc.w);
    acc.x = fmaf(p1.x, bf2f(q1.x), acc.x);
    acc.y = fmaf(p1.x, bf2f(q1.y), acc.y);
    acc.z = fmaf(p1.x, bf2f(q1.z), acc.z);
    acc.w = fmaf(p1.x, bf2f(q1.w), acc.w);
  }
  if (i < end) {
    float2 p = pairA[i];
    int d = __float_as_int(p.y);
    ushort4 q = *(const ushort4*)&hbf[(size_t)d * OUT_F + sl * 4];
    acc.x = fmaf(p.x, bf2f(q.x), acc.x);
    acc.y = fmaf(p.x, bf2f(q.y), acc.y);
    acc.z = fmaf(p.x, bf2f(q.z), acc.z);
    acc.w = fmaf(p.x, bf2f(q.w), acc.w);
  }
  if (node < N_NODES) {
    float4 o;
    o.x = acc.x > 0.f ? acc.x : expm1f(acc.x);
    o.y = acc.y > 0.f ? acc.y : expm1f(acc.y);
    o.z = acc.z > 0.f ? acc.z : expm1f(acc.z);
    o.w = acc.w > 0.f ? acc.w : expm1f(acc.w);
    *(float4*)(out + (size_t)node * OUT_F + sl * 4) = o;
  }
}

// ---------------------------------------------------------------------------
extern "C" void kernel_launch(void* const* d_in, const int* in_sizes, int n_in,
                              void* d_out, int out_size, void* d_ws,
                              size_t ws_size, hipStream_t stream) {
  const int* adj = (const int*)d_in[0];
  const float* x = (const float*)d_in[1];
  const float* W = (const float*)d_in[2];
  const float* b = (const float*)d_in[3];
  const float* a = (const float*)d_in[4];
  float* out = (float*)d_out;

  float* ws = (float*)d_ws;
  float* s1v = ws;                            // 100,000
  float* s2v = ws + 100000;                   // 100,000
  float* denom_r = ws + 200000;               // 100,000
  int* sfill = (int*)(ws + 300000);           // 782 (pad 800)
  int* dfill = (int*)(ws + 300800);           // 782 (pad 800)
  int2* rowbe = (int2*)(ws + 301600);         // 100,000 int2 = 200,000 f
  int* packS = (int*)(ws + 501600);           // 782*4480 int = 3,503,360
  int* packD = (int*)(ws + 4004960);          // 782*4480 int
  float2* pairA = (float2*)(ws + 7508320);    // 782*4480 float2 = 7,006,720 f
  u16* hbf = (u16*)(ws + 14515040);           // 6.4M u16 = 3.2M f
  u16* Wbf = (u16*)(ws + 17715040);           // 16,384 u16
  // total ~17.73M floats = 70.9 MB

  const int* src = adj;
  const int* dst = adj + N_EDGES;

  k_prep<<<65, 256, 0, stream>>>(W, Wbf, sfill, dfill);
  k_place<<<(N_EDGES + 1024 * EPT_P - 1) / (1024 * EPT_P), 1024, 0, stream>>>(
      src, dst, sfill, dfill, packS, packD);
  k_linear<<<(N_NODES + 63) / 64, 256, 0, stream>>>(x, Wbf, b, a, hbf, s1v, s2v);
  k_denom<<<NBKT, 256, 0, stream>>>(dfill, packD, s1v, s2v, denom_r);
  k_sort2<<<NBKT, 256, 0, stream>>>(sfill, packS, s1v, s2v, denom_r, pairA,
                                    rowbe);
  k_aggregate<<<(N_NODES + 15) / 16, 256, 0, stream>>>(rowbe, pairA, hbf, out);
}